// Round 1
// baseline (451.830 us; speedup 1.0000x reference)
//
#include <hip/hip_runtime.h>
#include <hip/hip_bf16.h>

#define NN 8192
#define DIN 512
#define HH 256
#define EE 262144
#define LN_EPS 1e-5f

// ---------------- CSR build ----------------
__global__ void count_edges(const int* __restrict__ src, int* __restrict__ cnt) {
    int k = blockIdx.x * 256 + threadIdx.x;
    if (k < EE) atomicAdd(&cnt[src[k]], 1);
}

__global__ __launch_bounds__(1024) void scan_deg(const int* __restrict__ deg, int* __restrict__ row_start) {
    __shared__ int sums[1024];
    int t = threadIdx.x;
    int base = t * 8;
    int loc[8];
    int s = 0;
#pragma unroll
    for (int i = 0; i < 8; i++) { loc[i] = s; s += deg[base + i]; }
    sums[t] = s;
    __syncthreads();
    for (int off = 1; off < 1024; off <<= 1) {
        int v = (t >= off) ? sums[t - off] : 0;
        __syncthreads();
        sums[t] += v;
        __syncthreads();
    }
    int excl = (t == 0) ? 0 : sums[t - 1];
#pragma unroll
    for (int i = 0; i < 8; i++) row_start[base + i] = excl + loc[i];
    if (t == 1023) row_start[NN] = sums[1023];
}

__global__ void fill_edges(const int* __restrict__ src, const int* __restrict__ tgt,
                           const int* __restrict__ row_start, int* __restrict__ cnt,
                           int* __restrict__ col) {
    int k = blockIdx.x * 256 + threadIdx.x;
    if (k < EE) {
        int s = src[k];
        int p = row_start[s] + atomicAdd(&cnt[s], 1);
        col[p] = tgt[k];
    }
}

// ---------------- fp32 GEMM: C[M,Nc] = A[M,K] @ B[Nc,K]^T + bias ----------------
__global__ __launch_bounds__(256) void gemm_nt(const float* __restrict__ A, const float* __restrict__ B,
                                               const float* __restrict__ bias, float* __restrict__ C,
                                               int M, int Nc, int K) {
    __shared__ float As[64][17];
    __shared__ float Bs[64][17];
    const int tid = threadIdx.x;
    const int tx = tid & 15, ty = tid >> 4;
    const int row0 = blockIdx.y * 64, col0 = blockIdx.x * 64;
    const int lr = tid >> 2;           // 0..63
    const int lc = (tid & 3) << 2;     // 0,4,8,12
    float acc[4][4] = {};
    const float* Arow = A + (size_t)(row0 + lr) * K + lc;
    const float* Brow = B + (size_t)(col0 + lr) * K + lc;
    for (int k0 = 0; k0 < K; k0 += 16) {
        float4 a4 = *(const float4*)(Arow + k0);
        float4 b4 = *(const float4*)(Brow + k0);
        As[lr][lc + 0] = a4.x; As[lr][lc + 1] = a4.y; As[lr][lc + 2] = a4.z; As[lr][lc + 3] = a4.w;
        Bs[lr][lc + 0] = b4.x; Bs[lr][lc + 1] = b4.y; Bs[lr][lc + 2] = b4.z; Bs[lr][lc + 3] = b4.w;
        __syncthreads();
#pragma unroll
        for (int kk = 0; kk < 16; kk++) {
            float av[4], bv[4];
#pragma unroll
            for (int i = 0; i < 4; i++) av[i] = As[ty * 4 + i][kk];
#pragma unroll
            for (int j = 0; j < 4; j++) bv[j] = Bs[tx * 4 + j][kk];
#pragma unroll
            for (int i = 0; i < 4; i++)
#pragma unroll
                for (int j = 0; j < 4; j++) acc[i][j] += av[i] * bv[j];
        }
        __syncthreads();
    }
#pragma unroll
    for (int i = 0; i < 4; i++) {
#pragma unroll
        for (int j = 0; j < 4; j++) {
            float v = acc[i][j];
            int cc = col0 + tx * 4 + j;
            if (bias) v += bias[cc];
            C[(size_t)(row0 + ty * 4 + i) * Nc + cc] = v;
        }
    }
}

// ---------------- scores s1,s2 + column sums S_total ----------------
// grid: NN/32 blocks, 256 threads (4 waves, 8 rows each)
__global__ __launch_bounds__(256) void score_kernel(const float* __restrict__ hw,
                                                    const float* __restrict__ a1, const float* __restrict__ a2,
                                                    float* __restrict__ s1, float* __restrict__ s2,
                                                    float* __restrict__ St) {
    int wave = threadIdx.x >> 6;
    int lane = threadIdx.x & 63;
    float a1v[4], a2v[4], cs[4] = {0.f, 0.f, 0.f, 0.f};
#pragma unroll
    for (int q = 0; q < 4; q++) { a1v[q] = a1[lane + 64 * q]; a2v[q] = a2[lane + 64 * q]; }
    int rbase = blockIdx.x * 32 + wave * 8;
    for (int rr = 0; rr < 8; rr++) {
        int r = rbase + rr;
        float d1 = 0.f, d2 = 0.f;
#pragma unroll
        for (int q = 0; q < 4; q++) {
            float v = hw[(size_t)r * HH + lane + 64 * q];
            cs[q] += v;
            d1 += v * a1v[q];
            d2 += v * a2v[q];
        }
        for (int off = 32; off > 0; off >>= 1) {
            d1 += __shfl_down(d1, off);
            d2 += __shfl_down(d2, off);
        }
        if (lane == 0) { s1[r] = d1; s2[r] = d2; }
    }
#pragma unroll
    for (int q = 0; q < 4; q++) atomicAdd(&St[lane + 64 * q], cs[q]);
}

// ---------------- fused GAT row: softmax-aggregate + residual + LN + ELU (+gate) ----------------
#define CHUNK 1024
__global__ __launch_bounds__(256) void gat_row(const float* __restrict__ hprev, const float* __restrict__ hw,
                                               const int* __restrict__ row_start, const int* __restrict__ col_idx,
                                               const float* __restrict__ s1, const float* __restrict__ s2,
                                               const float* __restrict__ St,
                                               const float* __restrict__ lng, const float* __restrict__ lnb,
                                               const float* __restrict__ W_pool, const float* __restrict__ b_pool,
                                               float* __restrict__ hout, float* __restrict__ gate, int last) {
    int i = blockIdx.x;
    int t = threadIdx.x;
    int beg = row_start[i], end = row_start[i + 1];
    int deg = end - beg;
    float s1i = s1[i];
    __shared__ float red[256];
    __shared__ float ws_w[CHUNK];
    __shared__ int ws_c[CHUNK];

    // Phase A: row max over edge scores (background zeros included via max with 0)
    float lmax = -1e30f;
    for (int k = beg + t; k < end; k += 256) {
        float e = s1i + s2[col_idx[k]];
        e = e > 0.f ? e : 0.2f * e;
        lmax = fmaxf(lmax, e);
    }
    red[t] = lmax;
    __syncthreads();
    for (int off = 128; off > 0; off >>= 1) {
        if (t < off) red[t] = fmaxf(red[t], red[t + off]);
        __syncthreads();
    }
    float m = fmaxf(red[0], 0.f);
    __syncthreads();

    // Phase B: sum exp(e - m)
    float lsum = 0.f;
    for (int k = beg + t; k < end; k += 256) {
        float e = s1i + s2[col_idx[k]];
        e = e > 0.f ? e : 0.2f * e;
        lsum += __expf(e - m);
    }
    red[t] = lsum;
    __syncthreads();
    for (int off = 128; off > 0; off >>= 1) {
        if (t < off) red[t] += red[t + off];
        __syncthreads();
    }
    float sumExp = red[0];
    __syncthreads();

    float em = __expf(-m);
    float Z = (float)(NN - deg) * em + sumExp;
    float invZ = 1.f / Z;
    float c = em * invZ;

    // Phase C: acc = c*S_total + sum_edges (p_k - c) * hw[tgt]
    float acc = c * St[t];
    for (int base = beg; base < end; base += CHUNK) {
        int cn = min(CHUNK, end - base);
        __syncthreads();
        for (int k = t; k < cn; k += 256) {
            int j = col_idx[base + k];
            float e = s1i + s2[j];
            e = e > 0.f ? e : 0.2f * e;
            ws_w[k] = __expf(e - m) * invZ - c;
            ws_c[k] = j;
        }
        __syncthreads();
        for (int k = 0; k < cn; k++) {
            acc += ws_w[k] * hw[(size_t)ws_c[k] * HH + t];
        }
    }

    // residual + LayerNorm + ELU
    float x = hprev[(size_t)i * HH + t] + acc;
    __syncthreads();
    red[t] = x;
    __syncthreads();
    for (int off = 128; off > 0; off >>= 1) {
        if (t < off) red[t] += red[t + off];
        __syncthreads();
    }
    float mu = red[0] * (1.f / HH);
    __syncthreads();
    float xm = x - mu;
    red[t] = xm * xm;
    __syncthreads();
    for (int off = 128; off > 0; off >>= 1) {
        if (t < off) red[t] += red[t + off];
        __syncthreads();
    }
    float var = red[0] * (1.f / HH);
    __syncthreads();
    float y = xm * rsqrtf(var + LN_EPS) * lng[t] + lnb[t];
    y = y > 0.f ? y : __expf(y) - 1.f;
    hout[(size_t)i * HH + t] = y;

    if (last) {
        red[t] = y * W_pool[t];
        __syncthreads();
        for (int off = 128; off > 0; off >>= 1) {
            if (t < off) red[t] += red[t + off];
            __syncthreads();
        }
        if (t == 0) {
            float g = red[0] + b_pool[0];
            gate[i] = 1.f / (1.f + __expf(-g));
        }
    }
}

// ---------------- pooling: graph_emb[c] = sum_i gate[i]*h[i][c] ----------------
__global__ __launch_bounds__(256) void pool_kernel(const float* __restrict__ h, const float* __restrict__ gate,
                                                   float* __restrict__ emb) {
    int c = threadIdx.x;
    int b = blockIdx.x;
    float acc = 0.f;
    for (int r = b * 256; r < (b + 1) * 256; r++) acc += gate[r] * h[(size_t)r * HH + c];
    atomicAdd(&emb[c], acc);
}

extern "C" void kernel_launch(void* const* d_in, const int* in_sizes, int n_in,
                              void* d_out, int out_size, void* d_ws, size_t ws_size,
                              hipStream_t stream) {
    const float* X      = (const float*)d_in[0];
    const int*   ei     = (const int*)d_in[1];
    const float* W_in   = (const float*)d_in[2];
    const float* b_in   = (const float*)d_in[3];
    const float* W_gat  = (const float*)d_in[4];
    const float* a_gat  = (const float*)d_in[5];
    const float* ln_g   = (const float*)d_in[6];
    const float* ln_b   = (const float*)d_in[7];
    const float* W_pool = (const float*)d_in[8];
    const float* b_pool = (const float*)d_in[9];
    float* out = (float*)d_out;

    float* wsf = (float*)d_ws;
    float* h   = wsf;
    float* hw  = h + (size_t)NN * HH;
    float* s1  = hw + (size_t)NN * HH;
    float* s2  = s1 + NN;
    float* St  = s2 + NN;
    float* gate = St + HH;
    int* row_start = (int*)(gate + NN);
    int* cnt = row_start + (NN + 1);
    int* col = cnt + NN;

    const int* src = ei;
    const int* tgt = ei + EE;

    // CSR build (same for both layers)
    hipMemsetAsync(cnt, 0, NN * sizeof(int), stream);
    count_edges<<<EE / 256, 256, 0, stream>>>(src, cnt);
    scan_deg<<<1, 1024, 0, stream>>>(cnt, row_start);
    hipMemsetAsync(cnt, 0, NN * sizeof(int), stream);
    fill_edges<<<EE / 256, 256, 0, stream>>>(src, tgt, row_start, cnt, col);

    // h = X @ W_in^T + b_in
    gemm_nt<<<dim3(HH / 64, NN / 64), 256, 0, stream>>>(X, W_in, b_in, h, NN, HH, DIN);

    for (int l = 0; l < 2; l++) {
        // hw = h @ W_gat[l]^T
        gemm_nt<<<dim3(HH / 64, NN / 64), 256, 0, stream>>>(h, W_gat + (size_t)l * HH * HH, nullptr, hw, NN, HH, HH);
        hipMemsetAsync(St, 0, HH * sizeof(float), stream);
        score_kernel<<<NN / 32, 256, 0, stream>>>(hw, a_gat + (size_t)l * 2 * HH, a_gat + (size_t)l * 2 * HH + HH,
                                                  s1, s2, St);
        float* hout = (l == 0) ? h : out;
        gat_row<<<NN, 256, 0, stream>>>(h, hw, row_start, col, s1, s2, St,
                                        ln_g + (size_t)l * HH, ln_b + (size_t)l * HH,
                                        W_pool, b_pool, hout, gate, (l == 1) ? 1 : 0);
    }

    hipMemsetAsync(out + (size_t)NN * HH, 0, HH * sizeof(float), stream);
    pool_kernel<<<NN / 256, 256, 0, stream>>>(out, gate, out + (size_t)NN * HH);
}

// Round 4
// 350.610 us; speedup vs baseline: 1.2887x; 1.2887x over previous
//
#include <hip/hip_runtime.h>
#include <hip/hip_bf16.h>
#include <stdint.h>

#define NN 8192
#define DIN 512
#define HH 256
#define EE 262144
#define LN_EPS 1e-5f

typedef __attribute__((ext_vector_type(8))) short bf16x8;
typedef __attribute__((ext_vector_type(4))) float f32x4;

__device__ __forceinline__ short f2bf_bits(float x) {
    __hip_bfloat16 b = __float2bfloat16(x);
    return __builtin_bit_cast(short, b);
}

// ---------------- fp32 -> bf16 convert (small weight matrices only) ----------------
__global__ __launch_bounds__(256) void f2b(const float* __restrict__ x, __hip_bfloat16* __restrict__ y, int n) {
    int base = (blockIdx.x * 256 + threadIdx.x) * 4;
    if (base < n) {
        float4 v = *(const float4*)(x + base);
        y[base + 0] = __float2bfloat16(v.x);
        y[base + 1] = __float2bfloat16(v.y);
        y[base + 2] = __float2bfloat16(v.z);
        y[base + 3] = __float2bfloat16(v.w);
    }
}

// ---------------- CSR build ----------------
__global__ void count_edges(const int* __restrict__ src, int* __restrict__ cnt) {
    int k = blockIdx.x * 256 + threadIdx.x;
    if (k < EE) atomicAdd(&cnt[src[k]], 1);
}

__global__ __launch_bounds__(1024) void scan_deg(const int* __restrict__ deg, int* __restrict__ row_start) {
    __shared__ int sums[1024];
    int t = threadIdx.x;
    int base = t * 8;
    int loc[8];
    int s = 0;
#pragma unroll
    for (int i = 0; i < 8; i++) { loc[i] = s; s += deg[base + i]; }
    sums[t] = s;
    __syncthreads();
    for (int off = 1; off < 1024; off <<= 1) {
        int v = (t >= off) ? sums[t - off] : 0;
        __syncthreads();
        sums[t] += v;
        __syncthreads();
    }
    int excl = (t == 0) ? 0 : sums[t - 1];
#pragma unroll
    for (int i = 0; i < 8; i++) row_start[base + i] = excl + loc[i];
    if (t == 1023) row_start[NN] = sums[1023];
}

__global__ void fill_edges(const int* __restrict__ src, const int* __restrict__ tgt,
                           const int* __restrict__ row_start, int* __restrict__ cnt,
                           int* __restrict__ col) {
    int k = blockIdx.x * 256 + threadIdx.x;
    if (k < EE) {
        int s = src[k];
        int p = row_start[s] + atomicAdd(&cnt[s], 1);
        col[p] = tgt[k];
    }
}

__device__ __forceinline__ void load16_lds(const void* g, void* l) {
    __builtin_amdgcn_global_load_lds((const __attribute__((address_space(1))) uint32_t*)g,
                                     (__attribute__((address_space(3))) uint32_t*)l, 16, 0, 0);
}

// ---------------- GEMM1: C[M,Nc] = A_f32[M,K] @ B_bf16[Nc,K]^T + bias -> bf16 ----------------
// 64x64 tile, BK=32, 4 waves each computing a 32x32 quadrant (2x2 of 16x16x32 MFMA).
__global__ __launch_bounds__(256) void gemm_f32a(const float* __restrict__ A,
                                                 const __hip_bfloat16* __restrict__ B,
                                                 const float* __restrict__ bias,
                                                 __hip_bfloat16* __restrict__ Cb,
                                                 int M, int Nc, int K) {
    __shared__ __hip_bfloat16 As[64 * 32];
    __shared__ __hip_bfloat16 Bs[64 * 32];
    const int tid = threadIdx.x;
    const int row0 = blockIdx.y * 64, col0 = blockIdx.x * 64;
    const int w = tid >> 6, l = tid & 63;
    const int quad = l >> 4, r = l & 15;
    const int mh = (w & 1) * 32, nh = (w >> 1) * 32;
    f32x4 acc[2][2] = {};

    const int srow = tid >> 2, scol = (tid & 3) * 8;
    const float* gA = A + (size_t)(row0 + srow) * K + scol;
    const __hip_bfloat16* gB = B + (size_t)(col0 + srow) * K + scol;
    __hip_bfloat16* lB = &Bs[tid * 8];
    __hip_bfloat16* lA = &As[tid * 8];

    for (int k0 = 0; k0 < K; k0 += 32) {
        load16_lds(gB + k0, lB);
        float4 a0 = *(const float4*)(gA + k0);
        float4 a1 = *(const float4*)(gA + k0 + 4);
        bf16x8 av;
        av[0] = f2bf_bits(a0.x); av[1] = f2bf_bits(a0.y);
        av[2] = f2bf_bits(a0.z); av[3] = f2bf_bits(a0.w);
        av[4] = f2bf_bits(a1.x); av[5] = f2bf_bits(a1.y);
        av[6] = f2bf_bits(a1.z); av[7] = f2bf_bits(a1.w);
        *(bf16x8*)lA = av;
        __syncthreads();
        bf16x8 aF[2], bF[2];
#pragma unroll
        for (int mi = 0; mi < 2; mi++)
            aF[mi] = *(const bf16x8*)&As[(mh + mi * 16 + r) * 32 + quad * 8];
#pragma unroll
        for (int ni = 0; ni < 2; ni++)
            bF[ni] = *(const bf16x8*)&Bs[(nh + ni * 16 + r) * 32 + quad * 8];
#pragma unroll
        for (int mi = 0; mi < 2; mi++)
#pragma unroll
            for (int ni = 0; ni < 2; ni++)
                acc[mi][ni] = __builtin_amdgcn_mfma_f32_16x16x32_bf16(aF[mi], bF[ni], acc[mi][ni], 0, 0, 0);
        __syncthreads();
    }

#pragma unroll
    for (int mi = 0; mi < 2; mi++)
#pragma unroll
        for (int ni = 0; ni < 2; ni++) {
            int gcol = col0 + nh + ni * 16 + r;
            float bv = bias ? bias[gcol] : 0.f;
#pragma unroll
            for (int reg = 0; reg < 4; reg++) {
                int grow = row0 + mh + mi * 16 + quad * 4 + reg;
                Cb[(size_t)grow * Nc + gcol] = __float2bfloat16(acc[mi][ni][reg] + bv);
            }
        }
}

// ---------------- layer GEMM: C_bf16 = A_bf16 @ B_bf16^T ----------------
__global__ __launch_bounds__(256) void gemm_bb(const __hip_bfloat16* __restrict__ A,
                                               const __hip_bfloat16* __restrict__ B,
                                               __hip_bfloat16* __restrict__ Cb,
                                               int M, int Nc, int K) {
    __shared__ __hip_bfloat16 As[64 * 32];
    __shared__ __hip_bfloat16 Bs[64 * 32];
    const int tid = threadIdx.x;
    const int row0 = blockIdx.y * 64, col0 = blockIdx.x * 64;
    const int w = tid >> 6, l = tid & 63;
    const int quad = l >> 4, r = l & 15;
    const int mh = (w & 1) * 32, nh = (w >> 1) * 32;
    f32x4 acc[2][2] = {};

    const int srow = tid >> 2, scol = (tid & 3) * 8;
    const __hip_bfloat16* gA = A + (size_t)(row0 + srow) * K + scol;
    const __hip_bfloat16* gB = B + (size_t)(col0 + srow) * K + scol;
    __hip_bfloat16* lA = &As[tid * 8];
    __hip_bfloat16* lB = &Bs[tid * 8];

    for (int k0 = 0; k0 < K; k0 += 32) {
        load16_lds(gA + k0, lA);
        load16_lds(gB + k0, lB);
        __syncthreads();
        bf16x8 aF[2], bF[2];
#pragma unroll
        for (int mi = 0; mi < 2; mi++)
            aF[mi] = *(const bf16x8*)&As[(mh + mi * 16 + r) * 32 + quad * 8];
#pragma unroll
        for (int ni = 0; ni < 2; ni++)
            bF[ni] = *(const bf16x8*)&Bs[(nh + ni * 16 + r) * 32 + quad * 8];
#pragma unroll
        for (int mi = 0; mi < 2; mi++)
#pragma unroll
            for (int ni = 0; ni < 2; ni++)
                acc[mi][ni] = __builtin_amdgcn_mfma_f32_16x16x32_bf16(aF[mi], bF[ni], acc[mi][ni], 0, 0, 0);
        __syncthreads();
    }

#pragma unroll
    for (int mi = 0; mi < 2; mi++)
#pragma unroll
        for (int ni = 0; ni < 2; ni++) {
            int gcol = col0 + nh + ni * 16 + r;
#pragma unroll
            for (int reg = 0; reg < 4; reg++) {
                int grow = row0 + mh + mi * 16 + quad * 4 + reg;
                Cb[(size_t)grow * Nc + gcol] = __float2bfloat16(acc[mi][ni][reg]);
            }
        }
}

// ---------------- scores s1,s2 + column sums S_total (bf16 hw) ----------------
__global__ __launch_bounds__(256) void score_kernel(const __hip_bfloat16* __restrict__ hw,
                                                    const float* __restrict__ a1, const float* __restrict__ a2,
                                                    float* __restrict__ s1, float* __restrict__ s2,
                                                    float* __restrict__ St) {
    int wave = threadIdx.x >> 6;
    int lane = threadIdx.x & 63;
    float a1v[4], a2v[4], cs[4] = {0.f, 0.f, 0.f, 0.f};
#pragma unroll
    for (int q = 0; q < 4; q++) { a1v[q] = a1[lane + 64 * q]; a2v[q] = a2[lane + 64 * q]; }
    int rbase = blockIdx.x * 32 + wave * 8;
    for (int rr = 0; rr < 8; rr++) {
        int r = rbase + rr;
        float d1 = 0.f, d2 = 0.f;
#pragma unroll
        for (int q = 0; q < 4; q++) {
            float v = __bfloat162float(hw[(size_t)r * HH + lane + 64 * q]);
            cs[q] += v;
            d1 += v * a1v[q];
            d2 += v * a2v[q];
        }
        for (int off = 32; off > 0; off >>= 1) {
            d1 += __shfl_down(d1, off);
            d2 += __shfl_down(d2, off);
        }
        if (lane == 0) { s1[r] = d1; s2[r] = d2; }
    }
#pragma unroll
    for (int q = 0; q < 4; q++) atomicAdd(&St[lane + 64 * q], cs[q]);
}

// ---------------- fused GAT row ----------------
#define CHUNK 1024
__global__ __launch_bounds__(256) void gat_row(const __hip_bfloat16* __restrict__ hprev,
                                               const __hip_bfloat16* __restrict__ hw,
                                               const int* __restrict__ row_start, const int* __restrict__ col_idx,
                                               const float* __restrict__ s1, const float* __restrict__ s2,
                                               const float* __restrict__ St,
                                               const float* __restrict__ lng, const float* __restrict__ lnb,
                                               const float* __restrict__ W_pool, const float* __restrict__ b_pool,
                                               float* __restrict__ houtf, __hip_bfloat16* __restrict__ houtb,
                                               float* __restrict__ gate, int last) {
    int i = blockIdx.x;
    int t = threadIdx.x;
    int beg = row_start[i], end = row_start[i + 1];
    int deg = end - beg;
    float s1i = s1[i];
    __shared__ float red[256];
    __shared__ float ws_w[CHUNK];
    __shared__ int ws_c[CHUNK];

    // Phase A: row max over edge scores
    float lmax = -1e30f;
    for (int k = beg + t; k < end; k += 256) {
        float e = s1i + s2[col_idx[k]];
        e = e > 0.f ? e : 0.2f * e;
        lmax = fmaxf(lmax, e);
    }
    red[t] = lmax;
    __syncthreads();
    for (int off = 128; off > 0; off >>= 1) {
        if (t < off) red[t] = fmaxf(red[t], red[t + off]);
        __syncthreads();
    }
    float m = fmaxf(red[0], 0.f);
    __syncthreads();

    // Phase B: sum exp(e - m)
    float lsum = 0.f;
    for (int k = beg + t; k < end; k += 256) {
        float e = s1i + s2[col_idx[k]];
        e = e > 0.f ? e : 0.2f * e;
        lsum += __expf(e - m);
    }
    red[t] = lsum;
    __syncthreads();
    for (int off = 128; off > 0; off >>= 1) {
        if (t < off) red[t] += red[t + off];
        __syncthreads();
    }
    float sumExp = red[0];
    __syncthreads();

    float em = __expf(-m);
    float Z = (float)(NN - deg) * em + sumExp;
    float invZ = 1.f / Z;
    float c = em * invZ;

    // Phase C: acc = c*S_total + sum_edges (p_k - c) * hw[tgt]
    float acc = c * St[t];
    for (int base = beg; base < end; base += CHUNK) {
        int cn = min(CHUNK, end - base);
        __syncthreads();
        for (int k = t; k < cn; k += 256) {
            int j = col_idx[base + k];
            float e = s1i + s2[j];
            e = e > 0.f ? e : 0.2f * e;
            ws_w[k] = __expf(e - m) * invZ - c;
            ws_c[k] = j;
        }
        __syncthreads();
        for (int k = 0; k < cn; k++) {
            acc += ws_w[k] * __bfloat162float(hw[(size_t)ws_c[k] * HH + t]);
        }
    }

    // residual + LayerNorm + ELU
    float x = __bfloat162float(hprev[(size_t)i * HH + t]) + acc;
    __syncthreads();
    red[t] = x;
    __syncthreads();
    for (int off = 128; off > 0; off >>= 1) {
        if (t < off) red[t] += red[t + off];
        __syncthreads();
    }
    float mu = red[0] * (1.f / HH);
    __syncthreads();
    float xm = x - mu;
    red[t] = xm * xm;
    __syncthreads();
    for (int off = 128; off > 0; off >>= 1) {
        if (t < off) red[t] += red[t + off];
        __syncthreads();
    }
    float var = red[0] * (1.f / HH);
    __syncthreads();
    float y = xm * rsqrtf(var + LN_EPS) * lng[t] + lnb[t];
    y = y > 0.f ? y : __expf(y) - 1.f;
    if (houtf) houtf[(size_t)i * HH + t] = y;
    houtb[(size_t)i * HH + t] = __float2bfloat16(y);

    if (last) {
        red[t] = y * W_pool[t];
        __syncthreads();
        for (int off = 128; off > 0; off >>= 1) {
            if (t < off) red[t] += red[t + off];
            __syncthreads();
        }
        if (t == 0) {
            float g = red[0] + b_pool[0];
            gate[i] = 1.f / (1.f + __expf(-g));
        }
    }
}

// ---------------- pooling ----------------
__global__ __launch_bounds__(256) void pool_kernel(const float* __restrict__ h, const float* __restrict__ gate,
                                                   float* __restrict__ emb) {
    int c = threadIdx.x;
    int b = blockIdx.x;
    float acc = 0.f;
    for (int r = b * 256; r < (b + 1) * 256; r++) acc += gate[r] * h[(size_t)r * HH + c];
    atomicAdd(&emb[c], acc);
}

extern "C" void kernel_launch(void* const* d_in, const int* in_sizes, int n_in,
                              void* d_out, int out_size, void* d_ws, size_t ws_size,
                              hipStream_t stream) {
    const float* X      = (const float*)d_in[0];
    const int*   ei     = (const int*)d_in[1];
    const float* W_in   = (const float*)d_in[2];
    const float* b_in   = (const float*)d_in[3];
    const float* W_gat  = (const float*)d_in[4];
    const float* a_gat  = (const float*)d_in[5];
    const float* ln_g   = (const float*)d_in[6];
    const float* ln_b   = (const float*)d_in[7];
    const float* W_pool = (const float*)d_in[8];
    const float* b_pool = (const float*)d_in[9];
    float* out = (float*)d_out;

    // ws layout (total ~9.7 MB): bf16 region first, then fp32, then int
    __hip_bfloat16* hb    = (__hip_bfloat16*)d_ws;            // NN*HH
    __hip_bfloat16* hwb   = hb + (size_t)NN * HH;             // NN*HH
    __hip_bfloat16* Wb_in = hwb + (size_t)NN * HH;            // HH*DIN
    __hip_bfloat16* Wgb   = Wb_in + (size_t)HH * DIN;         // 2*HH*HH
    float* wsf  = (float*)(Wgb + (size_t)2 * HH * HH);
    float* s1   = wsf;
    float* s2   = s1 + NN;
    float* St   = s2 + NN;
    float* gate = St + HH;
    int* row_start = (int*)(gate + NN);
    int* cnt = row_start + (NN + 1);
    int* col = cnt + NN;

    const int* src = ei;
    const int* tgt = ei + EE;

    // bf16 conversions of weights (small)
    f2b<<<(HH * DIN) / 1024, 256, 0, stream>>>(W_in, Wb_in, HH * DIN);
    f2b<<<(2 * HH * HH) / 1024, 256, 0, stream>>>(W_gat, Wgb, 2 * HH * HH);

    // CSR build
    hipMemsetAsync(cnt, 0, NN * sizeof(int), stream);
    count_edges<<<EE / 256, 256, 0, stream>>>(src, cnt);
    scan_deg<<<1, 1024, 0, stream>>>(cnt, row_start);
    hipMemsetAsync(cnt, 0, NN * sizeof(int), stream);
    fill_edges<<<EE / 256, 256, 0, stream>>>(src, tgt, row_start, cnt, col);

    // h = X @ W_in^T + b_in  (fp32 A, bf16 B, bf16 out)
    gemm_f32a<<<dim3(HH / 64, NN / 64), 256, 0, stream>>>(X, Wb_in, b_in, hb, NN, HH, DIN);

    for (int ll = 0; ll < 2; ll++) {
        gemm_bb<<<dim3(HH / 64, NN / 64), 256, 0, stream>>>(hb, Wgb + (size_t)ll * HH * HH, hwb, NN, HH, HH);
        hipMemsetAsync(St, 0, HH * sizeof(float), stream);
        score_kernel<<<NN / 32, 256, 0, stream>>>(hwb, a_gat + (size_t)ll * 2 * HH, a_gat + (size_t)ll * 2 * HH + HH,
                                                  s1, s2, St);
        gat_row<<<NN, 256, 0, stream>>>(hb, hwb, row_start, col, s1, s2, St,
                                        ln_g + (size_t)ll * HH, ln_b + (size_t)ll * HH,
                                        W_pool, b_pool,
                                        (ll == 1) ? out : nullptr, hb, gate, (ll == 1) ? 1 : 0);
    }

    hipMemsetAsync(out + (size_t)NN * HH, 0, HH * sizeof(float), stream);
    pool_kernel<<<NN / 256, 256, 0, stream>>>(out, gate, out + (size_t)NN * HH);
}

// Round 5
// 303.945 us; speedup vs baseline: 1.4866x; 1.1535x over previous
//
#include <hip/hip_runtime.h>
#include <hip/hip_bf16.h>
#include <stdint.h>

#define NN 8192
#define DIN 512
#define HH 256
#define EE 262144
#define LN_EPS 1e-5f

typedef __attribute__((ext_vector_type(8))) short bf16x8;
typedef __attribute__((ext_vector_type(4))) float f32x4;

__device__ __forceinline__ short f2bf_bits(float x) {
    __hip_bfloat16 b = __float2bfloat16(x);
    return __builtin_bit_cast(short, b);
}

// ---------------- fp32 -> bf16 convert (small weight matrices only) ----------------
__global__ __launch_bounds__(256) void f2b(const float* __restrict__ x, __hip_bfloat16* __restrict__ y, int n) {
    int base = (blockIdx.x * 256 + threadIdx.x) * 4;
    if (base < n) {
        float4 v = *(const float4*)(x + base);
        y[base + 0] = __float2bfloat16(v.x);
        y[base + 1] = __float2bfloat16(v.y);
        y[base + 2] = __float2bfloat16(v.z);
        y[base + 3] = __float2bfloat16(v.w);
    }
}

// ---------------- CSR build ----------------
__global__ void count_edges(const int* __restrict__ src, int* __restrict__ cnt) {
    int k = blockIdx.x * 256 + threadIdx.x;
    if (k < EE) atomicAdd(&cnt[src[k]], 1);
}

__global__ __launch_bounds__(1024) void scan_deg(const int* __restrict__ deg, int* __restrict__ row_start) {
    __shared__ int sums[1024];
    int t = threadIdx.x;
    int base = t * 8;
    int loc[8];
    int s = 0;
#pragma unroll
    for (int i = 0; i < 8; i++) { loc[i] = s; s += deg[base + i]; }
    sums[t] = s;
    __syncthreads();
    for (int off = 1; off < 1024; off <<= 1) {
        int v = (t >= off) ? sums[t - off] : 0;
        __syncthreads();
        sums[t] += v;
        __syncthreads();
    }
    int excl = (t == 0) ? 0 : sums[t - 1];
#pragma unroll
    for (int i = 0; i < 8; i++) row_start[base + i] = excl + loc[i];
    if (t == 1023) row_start[NN] = sums[1023];
}

__global__ void fill_edges(const int* __restrict__ src, const int* __restrict__ tgt,
                           const int* __restrict__ row_start, int* __restrict__ cnt,
                           int* __restrict__ col) {
    int k = blockIdx.x * 256 + threadIdx.x;
    if (k < EE) {
        int s = src[k];
        int p = row_start[s] + atomicAdd(&cnt[s], 1);
        col[p] = tgt[k];
    }
}

__device__ __forceinline__ void load16_lds(const void* g, void* l) {
    __builtin_amdgcn_global_load_lds((const __attribute__((address_space(1))) uint32_t*)g,
                                     (__attribute__((address_space(3))) uint32_t*)l, 16, 0, 0);
}

// ---------------- GEMM1: C[M,Nc] = A_f32[M,K] @ B_bf16[Nc,K]^T + bias -> bf16 ----------------
__global__ __launch_bounds__(256) void gemm_f32a(const float* __restrict__ A,
                                                 const __hip_bfloat16* __restrict__ B,
                                                 const float* __restrict__ bias,
                                                 __hip_bfloat16* __restrict__ Cb,
                                                 int M, int Nc, int K) {
    __shared__ __hip_bfloat16 As[64 * 32];
    __shared__ __hip_bfloat16 Bs[64 * 32];
    const int tid = threadIdx.x;
    const int row0 = blockIdx.y * 64, col0 = blockIdx.x * 64;
    const int w = tid >> 6, l = tid & 63;
    const int quad = l >> 4, r = l & 15;
    const int mh = (w & 1) * 32, nh = (w >> 1) * 32;
    f32x4 acc[2][2] = {};

    const int srow = tid >> 2, scol = (tid & 3) * 8;
    const float* gA = A + (size_t)(row0 + srow) * K + scol;
    const __hip_bfloat16* gB = B + (size_t)(col0 + srow) * K + scol;
    __hip_bfloat16* lB = &Bs[tid * 8];
    __hip_bfloat16* lA = &As[tid * 8];

    for (int k0 = 0; k0 < K; k0 += 32) {
        load16_lds(gB + k0, lB);
        float4 a0 = *(const float4*)(gA + k0);
        float4 a1 = *(const float4*)(gA + k0 + 4);
        bf16x8 av;
        av[0] = f2bf_bits(a0.x); av[1] = f2bf_bits(a0.y);
        av[2] = f2bf_bits(a0.z); av[3] = f2bf_bits(a0.w);
        av[4] = f2bf_bits(a1.x); av[5] = f2bf_bits(a1.y);
        av[6] = f2bf_bits(a1.z); av[7] = f2bf_bits(a1.w);
        *(bf16x8*)lA = av;
        __syncthreads();
        bf16x8 aF[2], bF[2];
#pragma unroll
        for (int mi = 0; mi < 2; mi++)
            aF[mi] = *(const bf16x8*)&As[(mh + mi * 16 + r) * 32 + quad * 8];
#pragma unroll
        for (int ni = 0; ni < 2; ni++)
            bF[ni] = *(const bf16x8*)&Bs[(nh + ni * 16 + r) * 32 + quad * 8];
#pragma unroll
        for (int mi = 0; mi < 2; mi++)
#pragma unroll
            for (int ni = 0; ni < 2; ni++)
                acc[mi][ni] = __builtin_amdgcn_mfma_f32_16x16x32_bf16(aF[mi], bF[ni], acc[mi][ni], 0, 0, 0);
        __syncthreads();
    }

#pragma unroll
    for (int mi = 0; mi < 2; mi++)
#pragma unroll
        for (int ni = 0; ni < 2; ni++) {
            int gcol = col0 + nh + ni * 16 + r;
            float bv = bias ? bias[gcol] : 0.f;
#pragma unroll
            for (int reg = 0; reg < 4; reg++) {
                int grow = row0 + mh + mi * 16 + quad * 4 + reg;
                Cb[(size_t)grow * Nc + gcol] = __float2bfloat16(acc[mi][ni][reg] + bv);
            }
        }
}

// ---------------- layer GEMM: C_bf16 = A_bf16 @ B_bf16^T ----------------
__global__ __launch_bounds__(256) void gemm_bb(const __hip_bfloat16* __restrict__ A,
                                               const __hip_bfloat16* __restrict__ B,
                                               __hip_bfloat16* __restrict__ Cb,
                                               int M, int Nc, int K) {
    __shared__ __hip_bfloat16 As[64 * 32];
    __shared__ __hip_bfloat16 Bs[64 * 32];
    const int tid = threadIdx.x;
    const int row0 = blockIdx.y * 64, col0 = blockIdx.x * 64;
    const int w = tid >> 6, l = tid & 63;
    const int quad = l >> 4, r = l & 15;
    const int mh = (w & 1) * 32, nh = (w >> 1) * 32;
    f32x4 acc[2][2] = {};

    const int srow = tid >> 2, scol = (tid & 3) * 8;
    const __hip_bfloat16* gA = A + (size_t)(row0 + srow) * K + scol;
    const __hip_bfloat16* gB = B + (size_t)(col0 + srow) * K + scol;
    __hip_bfloat16* lA = &As[tid * 8];
    __hip_bfloat16* lB = &Bs[tid * 8];

    for (int k0 = 0; k0 < K; k0 += 32) {
        load16_lds(gA + k0, lA);
        load16_lds(gB + k0, lB);
        __syncthreads();
        bf16x8 aF[2], bF[2];
#pragma unroll
        for (int mi = 0; mi < 2; mi++)
            aF[mi] = *(const bf16x8*)&As[(mh + mi * 16 + r) * 32 + quad * 8];
#pragma unroll
        for (int ni = 0; ni < 2; ni++)
            bF[ni] = *(const bf16x8*)&Bs[(nh + ni * 16 + r) * 32 + quad * 8];
#pragma unroll
        for (int mi = 0; mi < 2; mi++)
#pragma unroll
            for (int ni = 0; ni < 2; ni++)
                acc[mi][ni] = __builtin_amdgcn_mfma_f32_16x16x32_bf16(aF[mi], bF[ni], acc[mi][ni], 0, 0, 0);
        __syncthreads();
    }

#pragma unroll
    for (int mi = 0; mi < 2; mi++)
#pragma unroll
        for (int ni = 0; ni < 2; ni++) {
            int gcol = col0 + nh + ni * 16 + r;
#pragma unroll
            for (int reg = 0; reg < 4; reg++) {
                int grow = row0 + mh + mi * 16 + quad * 4 + reg;
                Cb[(size_t)grow * Nc + gcol] = __float2bfloat16(acc[mi][ni][reg]);
            }
        }
}

// ---------------- scores s1,s2 + column sums S_total (bf16 hw) ----------------
__global__ __launch_bounds__(256) void score_kernel(const __hip_bfloat16* __restrict__ hw,
                                                    const float* __restrict__ a1, const float* __restrict__ a2,
                                                    float* __restrict__ s1, float* __restrict__ s2,
                                                    float* __restrict__ St) {
    int wave = threadIdx.x >> 6;
    int lane = threadIdx.x & 63;
    float a1v[4], a2v[4], cs[4] = {0.f, 0.f, 0.f, 0.f};
#pragma unroll
    for (int q = 0; q < 4; q++) { a1v[q] = a1[lane + 64 * q]; a2v[q] = a2[lane + 64 * q]; }
    int rbase = blockIdx.x * 32 + wave * 8;
    for (int rr = 0; rr < 8; rr++) {
        int r = rbase + rr;
        float d1 = 0.f, d2 = 0.f;
#pragma unroll
        for (int q = 0; q < 4; q++) {
            float v = __bfloat162float(hw[(size_t)r * HH + lane + 64 * q]);
            cs[q] += v;
            d1 += v * a1v[q];
            d2 += v * a2v[q];
        }
        for (int off = 32; off > 0; off >>= 1) {
            d1 += __shfl_down(d1, off);
            d2 += __shfl_down(d2, off);
        }
        if (lane == 0) { s1[r] = d1; s2[r] = d2; }
    }
#pragma unroll
    for (int q = 0; q < 4; q++) atomicAdd(&St[lane + 64 * q], cs[q]);
}

// ---------------- fused GAT row ----------------
#define CHUNK 1024
__global__ __launch_bounds__(256) void gat_row(const __hip_bfloat16* __restrict__ hprev,
                                               const __hip_bfloat16* __restrict__ hw,
                                               const int* __restrict__ row_start, const int* __restrict__ col_idx,
                                               const float* __restrict__ s1, const float* __restrict__ s2,
                                               const float* __restrict__ St,
                                               const float* __restrict__ lng, const float* __restrict__ lnb,
                                               const float* __restrict__ W_pool, const float* __restrict__ b_pool,
                                               float* __restrict__ houtf, __hip_bfloat16* __restrict__ houtb,
                                               float* __restrict__ gate, int last) {
    int i = blockIdx.x;
    int t = threadIdx.x;
    int beg = row_start[i], end = row_start[i + 1];
    int deg = end - beg;
    float s1i = s1[i];
    __shared__ float red[256];
    __shared__ float ws_w[CHUNK];
    __shared__ int ws_c[CHUNK];

    // Phase A: row max over edge scores
    float lmax = -1e30f;
    for (int k = beg + t; k < end; k += 256) {
        float e = s1i + s2[col_idx[k]];
        e = e > 0.f ? e : 0.2f * e;
        lmax = fmaxf(lmax, e);
    }
    red[t] = lmax;
    __syncthreads();
    for (int off = 128; off > 0; off >>= 1) {
        if (t < off) red[t] = fmaxf(red[t], red[t + off]);
        __syncthreads();
    }
    float m = fmaxf(red[0], 0.f);
    __syncthreads();

    // Phase B: sum exp(e - m)
    float lsum = 0.f;
    for (int k = beg + t; k < end; k += 256) {
        float e = s1i + s2[col_idx[k]];
        e = e > 0.f ? e : 0.2f * e;
        lsum += __expf(e - m);
    }
    red[t] = lsum;
    __syncthreads();
    for (int off = 128; off > 0; off >>= 1) {
        if (t < off) red[t] += red[t + off];
        __syncthreads();
    }
    float sumExp = red[0];
    __syncthreads();

    float em = __expf(-m);
    float Z = (float)(NN - deg) * em + sumExp;
    float invZ = 1.f / Z;
    float c = em * invZ;

    // Phase C: acc = c*S_total + sum_edges (p_k - c) * hw[tgt]
    float acc = c * St[t];
    for (int base = beg; base < end; base += CHUNK) {
        int cn = min(CHUNK, end - base);
        __syncthreads();
        for (int k = t; k < cn; k += 256) {
            int j = col_idx[base + k];
            float e = s1i + s2[j];
            e = e > 0.f ? e : 0.2f * e;
            ws_w[k] = __expf(e - m) * invZ - c;
            ws_c[k] = j;
        }
        __syncthreads();
        for (int k = 0; k < cn; k++) {
            acc += ws_w[k] * __bfloat162float(hw[(size_t)ws_c[k] * HH + t]);
        }
    }

    // residual + LayerNorm + ELU
    float x = __bfloat162float(hprev[(size_t)i * HH + t]) + acc;
    __syncthreads();
    red[t] = x;
    __syncthreads();
    for (int off = 128; off > 0; off >>= 1) {
        if (t < off) red[t] += red[t + off];
        __syncthreads();
    }
    float mu = red[0] * (1.f / HH);
    __syncthreads();
    float xm = x - mu;
    red[t] = xm * xm;
    __syncthreads();
    for (int off = 128; off > 0; off >>= 1) {
        if (t < off) red[t] += red[t + off];
        __syncthreads();
    }
    float var = red[0] * (1.f / HH);
    __syncthreads();
    float y = xm * rsqrtf(var + LN_EPS) * lng[t] + lnb[t];
    y = y > 0.f ? y : __expf(y) - 1.f;
    if (houtf) houtf[(size_t)i * HH + t] = y;
    houtb[(size_t)i * HH + t] = __float2bfloat16(y);

    if (last) {
        red[t] = y * W_pool[t];
        __syncthreads();
        for (int off = 128; off > 0; off >>= 1) {
            if (t < off) red[t] += red[t + off];
            __syncthreads();
        }
        if (t == 0) {
            float g = red[0] + b_pool[0];
            gate[i] = 1.f / (1.f + __expf(-g));
        }
    }
}

// ---------------- pooling: 256 blocks x 32 rows, unrolled ----------------
__global__ __launch_bounds__(256) void pool_kernel(const float* __restrict__ h, const float* __restrict__ gate,
                                                   float* __restrict__ emb) {
    int c = threadIdx.x;
    int r0 = blockIdx.x * 32;
    float acc = 0.f;
#pragma unroll
    for (int rr = 0; rr < 32; rr++) {
        int r = r0 + rr;
        acc += gate[r] * h[(size_t)r * HH + c];
    }
    atomicAdd(&emb[c], acc);
}

extern "C" void kernel_launch(void* const* d_in, const int* in_sizes, int n_in,
                              void* d_out, int out_size, void* d_ws, size_t ws_size,
                              hipStream_t stream) {
    const float* X      = (const float*)d_in[0];
    const int*   ei     = (const int*)d_in[1];
    const float* W_in   = (const float*)d_in[2];
    const float* b_in   = (const float*)d_in[3];
    const float* W_gat  = (const float*)d_in[4];
    const float* a_gat  = (const float*)d_in[5];
    const float* ln_g   = (const float*)d_in[6];
    const float* ln_b   = (const float*)d_in[7];
    const float* W_pool = (const float*)d_in[8];
    const float* b_pool = (const float*)d_in[9];
    float* out = (float*)d_out;

    // ws layout (total ~9.7 MB): bf16 region first, then fp32, then int
    __hip_bfloat16* hb    = (__hip_bfloat16*)d_ws;            // NN*HH
    __hip_bfloat16* hwb   = hb + (size_t)NN * HH;             // NN*HH
    __hip_bfloat16* Wb_in = hwb + (size_t)NN * HH;            // HH*DIN
    __hip_bfloat16* Wgb   = Wb_in + (size_t)HH * DIN;         // 2*HH*HH
    float* wsf  = (float*)(Wgb + (size_t)2 * HH * HH);
    float* s1   = wsf;
    float* s2   = s1 + NN;
    float* St   = s2 + NN;
    float* gate = St + HH;
    int* row_start = (int*)(gate + NN);
    int* cnt = row_start + (NN + 1);
    int* col = cnt + NN;

    const int* src = ei;
    const int* tgt = ei + EE;

    // bf16 conversions of weights (small)
    f2b<<<(HH * DIN) / 1024, 256, 0, stream>>>(W_in, Wb_in, HH * DIN);
    f2b<<<(2 * HH * HH) / 1024, 256, 0, stream>>>(W_gat, Wgb, 2 * HH * HH);

    // CSR build
    hipMemsetAsync(cnt, 0, NN * sizeof(int), stream);
    count_edges<<<EE / 256, 256, 0, stream>>>(src, cnt);
    scan_deg<<<1, 1024, 0, stream>>>(cnt, row_start);
    hipMemsetAsync(cnt, 0, NN * sizeof(int), stream);
    fill_edges<<<EE / 256, 256, 0, stream>>>(src, tgt, row_start, cnt, col);

    // h = X @ W_in^T + b_in  (fp32 A, bf16 B, bf16 out)
    gemm_f32a<<<dim3(HH / 64, NN / 64), 256, 0, stream>>>(X, Wb_in, b_in, hb, NN, HH, DIN);

    for (int ll = 0; ll < 2; ll++) {
        gemm_bb<<<dim3(HH / 64, NN / 64), 256, 0, stream>>>(hb, Wgb + (size_t)ll * HH * HH, hwb, NN, HH, HH);
        hipMemsetAsync(St, 0, HH * sizeof(float), stream);
        score_kernel<<<NN / 32, 256, 0, stream>>>(hwb, a_gat + (size_t)ll * 2 * HH, a_gat + (size_t)ll * 2 * HH + HH,
                                                  s1, s2, St);
        gat_row<<<NN, 256, 0, stream>>>(hb, hwb, row_start, col, s1, s2, St,
                                        ln_g + (size_t)ll * HH, ln_b + (size_t)ll * HH,
                                        W_pool, b_pool,
                                        (ll == 1) ? out : nullptr, hb, gate, (ll == 1) ? 1 : 0);
    }

    hipMemsetAsync(out + (size_t)NN * HH, 0, HH * sizeof(float), stream);
    pool_kernel<<<NN / 32, 256, 0, stream>>>(out, gate, out + (size_t)NN * HH);
}

// Round 6
// 207.964 us; speedup vs baseline: 2.1726x; 1.4615x over previous
//
#include <hip/hip_runtime.h>
#include <hip/hip_bf16.h>
#include <stdint.h>

#define NN 8192
#define DIN 512
#define HH 256
#define EE 262144
#define LN_EPS 1e-5f

typedef __attribute__((ext_vector_type(8))) short bf16x8;
typedef __attribute__((ext_vector_type(4))) short s16x4;
typedef __attribute__((ext_vector_type(4))) float f32x4;

__device__ __forceinline__ short f2bf_bits(float x) {
    __hip_bfloat16 b = __float2bfloat16(x);
    return __builtin_bit_cast(short, b);
}
__device__ __forceinline__ float bf2f(short s) {
    uint32_t u = ((uint32_t)(uint16_t)s) << 16;
    return __builtin_bit_cast(float, u);
}

// ---------------- fused weight conversion (W_in and W_gat) ----------------
__global__ __launch_bounds__(256) void f2b2(const float* __restrict__ x1, __hip_bfloat16* __restrict__ y1, int n1,
                                            const float* __restrict__ x2, __hip_bfloat16* __restrict__ y2, int n2) {
    int base = (blockIdx.x * 256 + threadIdx.x) * 4;
    const float* x; __hip_bfloat16* y; int b;
    if (base < n1) { x = x1; y = y1; b = base; }
    else { b = base - n1; if (b >= n2) return; x = x2; y = y2; }
    float4 v = *(const float4*)(x + b);
    y[b + 0] = __float2bfloat16(v.x);
    y[b + 1] = __float2bfloat16(v.y);
    y[b + 2] = __float2bfloat16(v.z);
    y[b + 3] = __float2bfloat16(v.w);
}

// ---------------- CSR build ----------------
__global__ void count_edges(const int* __restrict__ src, int* __restrict__ cnt) {
    int k = blockIdx.x * 256 + threadIdx.x;
    if (k < EE) atomicAdd(&cnt[src[k]], 1);
}

__global__ __launch_bounds__(1024) void scan_deg(const int* __restrict__ deg, int* __restrict__ row_start) {
    __shared__ int sums[1024];
    int t = threadIdx.x;
    int base = t * 8;
    int loc[8];
    int s = 0;
#pragma unroll
    for (int i = 0; i < 8; i++) { loc[i] = s; s += deg[base + i]; }
    sums[t] = s;
    __syncthreads();
    for (int off = 1; off < 1024; off <<= 1) {
        int v = (t >= off) ? sums[t - off] : 0;
        __syncthreads();
        sums[t] += v;
        __syncthreads();
    }
    int excl = (t == 0) ? 0 : sums[t - 1];
#pragma unroll
    for (int i = 0; i < 8; i++) row_start[base + i] = excl + loc[i];
    if (t == 1023) row_start[NN] = sums[1023];
}

__global__ void fill_edges(const int* __restrict__ src, const int* __restrict__ tgt,
                           const int* __restrict__ row_start, int* __restrict__ cnt,
                           int* __restrict__ col) {
    int k = blockIdx.x * 256 + threadIdx.x;
    if (k < EE) {
        int s = src[k];
        int p = row_start[s] + atomicAdd(&cnt[s], 1);
        col[p] = tgt[k];
    }
}

__device__ __forceinline__ void load16_lds(const void* g, void* l) {
    __builtin_amdgcn_global_load_lds((const __attribute__((address_space(1))) uint32_t*)g,
                                     (__attribute__((address_space(3))) uint32_t*)l, 16, 0, 0);
}

// ---------------- GEMM1: C[M,Nc] = A_f32[M,K] @ B_bf16[Nc,K]^T + bias -> bf16 ----------------
__global__ __launch_bounds__(256) void gemm_f32a(const float* __restrict__ A,
                                                 const __hip_bfloat16* __restrict__ B,
                                                 const float* __restrict__ bias,
                                                 __hip_bfloat16* __restrict__ Cb,
                                                 int M, int Nc, int K) {
    __shared__ __hip_bfloat16 As[64 * 32];
    __shared__ __hip_bfloat16 Bs[64 * 32];
    const int tid = threadIdx.x;
    const int row0 = blockIdx.y * 64, col0 = blockIdx.x * 64;
    const int w = tid >> 6, l = tid & 63;
    const int quad = l >> 4, r = l & 15;
    const int mh = (w & 1) * 32, nh = (w >> 1) * 32;
    f32x4 acc[2][2] = {};

    const int srow = tid >> 2, scol = (tid & 3) * 8;
    const float* gA = A + (size_t)(row0 + srow) * K + scol;
    const __hip_bfloat16* gB = B + (size_t)(col0 + srow) * K + scol;
    __hip_bfloat16* lB = &Bs[tid * 8];
    __hip_bfloat16* lA = &As[tid * 8];

    for (int k0 = 0; k0 < K; k0 += 32) {
        load16_lds(gB + k0, lB);
        float4 a0 = *(const float4*)(gA + k0);
        float4 a1 = *(const float4*)(gA + k0 + 4);
        bf16x8 av;
        av[0] = f2bf_bits(a0.x); av[1] = f2bf_bits(a0.y);
        av[2] = f2bf_bits(a0.z); av[3] = f2bf_bits(a0.w);
        av[4] = f2bf_bits(a1.x); av[5] = f2bf_bits(a1.y);
        av[6] = f2bf_bits(a1.z); av[7] = f2bf_bits(a1.w);
        *(bf16x8*)lA = av;
        __syncthreads();
        bf16x8 aF[2], bF[2];
#pragma unroll
        for (int mi = 0; mi < 2; mi++)
            aF[mi] = *(const bf16x8*)&As[(mh + mi * 16 + r) * 32 + quad * 8];
#pragma unroll
        for (int ni = 0; ni < 2; ni++)
            bF[ni] = *(const bf16x8*)&Bs[(nh + ni * 16 + r) * 32 + quad * 8];
#pragma unroll
        for (int mi = 0; mi < 2; mi++)
#pragma unroll
            for (int ni = 0; ni < 2; ni++)
                acc[mi][ni] = __builtin_amdgcn_mfma_f32_16x16x32_bf16(aF[mi], bF[ni], acc[mi][ni], 0, 0, 0);
        __syncthreads();
    }

#pragma unroll
    for (int mi = 0; mi < 2; mi++)
#pragma unroll
        for (int ni = 0; ni < 2; ni++) {
            int gcol = col0 + nh + ni * 16 + r;
            float bv = bias[gcol];
#pragma unroll
            for (int reg = 0; reg < 4; reg++) {
                int grow = row0 + mh + mi * 16 + quad * 4 + reg;
                Cb[(size_t)grow * Nc + gcol] = __float2bfloat16(acc[mi][ni][reg] + bv);
            }
        }
}

// ---------------- layer GEMM + fused score epilogue ----------------
// C_bf16 = A_bf16 @ B_bf16^T; also accumulates s1[row] += sum_c C*a1[c],
// s2[row] += sum_c C*a2[c], St[col] += sum_r C via atomics (zero-init'd).
__global__ __launch_bounds__(256) void gemm_bb_score(const __hip_bfloat16* __restrict__ A,
                                                     const __hip_bfloat16* __restrict__ B,
                                                     __hip_bfloat16* __restrict__ Cb,
                                                     const float* __restrict__ ag1,
                                                     const float* __restrict__ ag2,
                                                     float* __restrict__ s1, float* __restrict__ s2,
                                                     float* __restrict__ St,
                                                     int M, int Nc, int K) {
    __shared__ __hip_bfloat16 As[64 * 32];
    __shared__ __hip_bfloat16 Bs[64 * 32];
    const int tid = threadIdx.x;
    const int row0 = blockIdx.y * 64, col0 = blockIdx.x * 64;
    const int w = tid >> 6, l = tid & 63;
    const int quad = l >> 4, r = l & 15;
    const int mh = (w & 1) * 32, nh = (w >> 1) * 32;
    f32x4 acc[2][2] = {};

    const int srow = tid >> 2, scol = (tid & 3) * 8;
    const __hip_bfloat16* gA = A + (size_t)(row0 + srow) * K + scol;
    const __hip_bfloat16* gB = B + (size_t)(col0 + srow) * K + scol;
    __hip_bfloat16* lA = &As[tid * 8];
    __hip_bfloat16* lB = &Bs[tid * 8];

    for (int k0 = 0; k0 < K; k0 += 32) {
        load16_lds(gA + k0, lA);
        load16_lds(gB + k0, lB);
        __syncthreads();
        bf16x8 aF[2], bF[2];
#pragma unroll
        for (int mi = 0; mi < 2; mi++)
            aF[mi] = *(const bf16x8*)&As[(mh + mi * 16 + r) * 32 + quad * 8];
#pragma unroll
        for (int ni = 0; ni < 2; ni++)
            bF[ni] = *(const bf16x8*)&Bs[(nh + ni * 16 + r) * 32 + quad * 8];
#pragma unroll
        for (int mi = 0; mi < 2; mi++)
#pragma unroll
            for (int ni = 0; ni < 2; ni++)
                acc[mi][ni] = __builtin_amdgcn_mfma_f32_16x16x32_bf16(aF[mi], bF[ni], acc[mi][ni], 0, 0, 0);
        __syncthreads();
    }

    // C write
#pragma unroll
    for (int mi = 0; mi < 2; mi++)
#pragma unroll
        for (int ni = 0; ni < 2; ni++) {
            int gcol = col0 + nh + ni * 16 + r;
#pragma unroll
            for (int reg = 0; reg < 4; reg++) {
                int grow = row0 + mh + mi * 16 + quad * 4 + reg;
                Cb[(size_t)grow * Nc + gcol] = __float2bfloat16(acc[mi][ni][reg]);
            }
        }

    // fused score: s1/s2 row partials over this block's 64 cols
    float a1v[2], a2v[2];
#pragma unroll
    for (int ni = 0; ni < 2; ni++) {
        int gcol = col0 + nh + ni * 16 + r;
        a1v[ni] = ag1[gcol];
        a2v[ni] = ag2[gcol];
    }
#pragma unroll
    for (int mi = 0; mi < 2; mi++)
#pragma unroll
        for (int reg = 0; reg < 4; reg++) {
            float p1 = acc[mi][0][reg] * a1v[0] + acc[mi][1][reg] * a1v[1];
            float p2 = acc[mi][0][reg] * a2v[0] + acc[mi][1][reg] * a2v[1];
#pragma unroll
            for (int off = 1; off <= 8; off <<= 1) {
                p1 += __shfl_xor(p1, off);
                p2 += __shfl_xor(p2, off);
            }
            if (r == 0) {
                int grow = row0 + mh + mi * 16 + quad * 4 + reg;
                atomicAdd(&s1[grow], p1);
                atomicAdd(&s2[grow], p2);
            }
        }
    // St col partials over this block's (wave's) 32 rows
#pragma unroll
    for (int ni = 0; ni < 2; ni++) {
        float pS = 0.f;
#pragma unroll
        for (int mi = 0; mi < 2; mi++)
#pragma unroll
            for (int reg = 0; reg < 4; reg++) pS += acc[mi][ni][reg];
        pS += __shfl_xor(pS, 16);
        pS += __shfl_xor(pS, 32);
        if (quad == 0) atomicAdd(&St[col0 + nh + ni * 16 + r], pS);
    }
}

// ---------------- wave-per-row GAT: softmax-aggregate + residual + LN + ELU (+gate) ----------------
// 1 row = 1 wave (64 lanes x 4 channels). No LDS, no __syncthreads.
__global__ __launch_bounds__(256) void gat_row(const __hip_bfloat16* __restrict__ hprev,
                                               const __hip_bfloat16* __restrict__ hw,
                                               const int* __restrict__ row_start, const int* __restrict__ col_idx,
                                               const float* __restrict__ s1, const float* __restrict__ s2,
                                               const float* __restrict__ St,
                                               const float* __restrict__ lng, const float* __restrict__ lnb,
                                               const float* __restrict__ W_pool, const float* __restrict__ b_pool,
                                               float* __restrict__ houtf, __hip_bfloat16* __restrict__ houtb,
                                               float* __restrict__ gate, int last) {
    const int wv = threadIdx.x >> 6, lane = threadIdx.x & 63;
    const int i = blockIdx.x * 4 + wv;
    const int beg = row_start[i], end = row_start[i + 1];
    const int deg = end - beg;
    const float s1i = s1[i];

    // Phase A: max over edge scores (0 background included via init)
    float lmax = 0.f;
    for (int k = beg + lane; k < end; k += 64) {
        float e = s1i + s2[col_idx[k]];
        e = e > 0.f ? e : 0.2f * e;
        lmax = fmaxf(lmax, e);
    }
#pragma unroll
    for (int off = 32; off; off >>= 1) lmax = fmaxf(lmax, __shfl_xor(lmax, off));
    const float m = lmax;

    // Phase B: sum exp(e - m)
    float lsum = 0.f;
    for (int k = beg + lane; k < end; k += 64) {
        float e = s1i + s2[col_idx[k]];
        e = e > 0.f ? e : 0.2f * e;
        lsum += __expf(e - m);
    }
#pragma unroll
    for (int off = 32; off; off >>= 1) lsum += __shfl_xor(lsum, off);

    const float em = __expf(-m);
    const float Z = (float)(NN - deg) * em + lsum;
    const float invZ = 1.f / Z;
    const float c = em * invZ;

    // Phase C: acc = c*St + sum_edges (p_k - c) * hw[tgt]; lane owns channels 4*lane..+3
    const float4 Stv = *(const float4*)(St + 4 * lane);
    float ac0 = c * Stv.x, ac1 = c * Stv.y, ac2 = c * Stv.z, ac3 = c * Stv.w;
    const short* hws = (const short*)hw;

    for (int kb = beg; kb < end; kb += 64) {
        int k = kb + lane;
        float wk = 0.f;
        int ck = 0;
        if (k < end) {
            int j = col_idx[k];
            float e = s1i + s2[j];
            e = e > 0.f ? e : 0.2f * e;
            wk = __expf(e - m) * invZ - c;
            ck = j;
        }
        int nb = min(64, end - kb);
#pragma unroll 4
        for (int jj = 0; jj < nb; jj++) {
            float wj = __shfl(wk, jj);
            int cj = __shfl(ck, jj);
            s16x4 hv = *(const s16x4*)(hws + (size_t)cj * HH + 4 * lane);
            ac0 += wj * bf2f(hv[0]);
            ac1 += wj * bf2f(hv[1]);
            ac2 += wj * bf2f(hv[2]);
            ac3 += wj * bf2f(hv[3]);
        }
    }

    // residual + LayerNorm + ELU
    s16x4 hp = *(const s16x4*)((const short*)hprev + (size_t)i * HH + 4 * lane);
    float x0 = bf2f(hp[0]) + ac0;
    float x1 = bf2f(hp[1]) + ac1;
    float x2 = bf2f(hp[2]) + ac2;
    float x3 = bf2f(hp[3]) + ac3;
    float ssum = x0 + x1 + x2 + x3;
#pragma unroll
    for (int off = 32; off; off >>= 1) ssum += __shfl_xor(ssum, off);
    float mu = ssum * (1.f / HH);
    float d0 = x0 - mu, d1 = x1 - mu, d2 = x2 - mu, d3 = x3 - mu;
    float vsum = d0 * d0 + d1 * d1 + d2 * d2 + d3 * d3;
#pragma unroll
    for (int off = 32; off; off >>= 1) vsum += __shfl_xor(vsum, off);
    float rstd = rsqrtf(vsum * (1.f / HH) + LN_EPS);
    float4 g4 = *(const float4*)(lng + 4 * lane);
    float4 b4 = *(const float4*)(lnb + 4 * lane);
    float y0 = d0 * rstd * g4.x + b4.x;
    float y1 = d1 * rstd * g4.y + b4.y;
    float y2 = d2 * rstd * g4.z + b4.z;
    float y3 = d3 * rstd * g4.w + b4.w;
    y0 = y0 > 0.f ? y0 : __expf(y0) - 1.f;
    y1 = y1 > 0.f ? y1 : __expf(y1) - 1.f;
    y2 = y2 > 0.f ? y2 : __expf(y2) - 1.f;
    y3 = y3 > 0.f ? y3 : __expf(y3) - 1.f;

    s16x4 yv;
    yv[0] = f2bf_bits(y0); yv[1] = f2bf_bits(y1); yv[2] = f2bf_bits(y2); yv[3] = f2bf_bits(y3);
    *(s16x4*)((short*)houtb + (size_t)i * HH + 4 * lane) = yv;
    if (houtf) {
        float4 yf = { y0, y1, y2, y3 };
        *(float4*)(houtf + (size_t)i * HH + 4 * lane) = yf;
    }

    if (last) {
        float4 wp = *(const float4*)(W_pool + 4 * lane);
        float p = y0 * wp.x + y1 * wp.y + y2 * wp.z + y3 * wp.w;
#pragma unroll
        for (int off = 32; off; off >>= 1) p += __shfl_xor(p, off);
        if (lane == 0) {
            float g = p + b_pool[0];
            gate[i] = 1.f / (1.f + __expf(-g));
        }
    }
}

// ---------------- pooling: 256 blocks x 32 rows, unrolled ----------------
__global__ __launch_bounds__(256) void pool_kernel(const float* __restrict__ h, const float* __restrict__ gate,
                                                   float* __restrict__ emb) {
    int c = threadIdx.x;
    int r0 = blockIdx.x * 32;
    float acc = 0.f;
#pragma unroll
    for (int rr = 0; rr < 32; rr++) {
        int r = r0 + rr;
        acc += gate[r] * h[(size_t)r * HH + c];
    }
    atomicAdd(&emb[c], acc);
}

extern "C" void kernel_launch(void* const* d_in, const int* in_sizes, int n_in,
                              void* d_out, int out_size, void* d_ws, size_t ws_size,
                              hipStream_t stream) {
    const float* X      = (const float*)d_in[0];
    const int*   ei     = (const int*)d_in[1];
    const float* W_in   = (const float*)d_in[2];
    const float* b_in   = (const float*)d_in[3];
    const float* W_gat  = (const float*)d_in[4];
    const float* a_gat  = (const float*)d_in[5];
    const float* ln_g   = (const float*)d_in[6];
    const float* ln_b   = (const float*)d_in[7];
    const float* W_pool = (const float*)d_in[8];
    const float* b_pool = (const float*)d_in[9];
    float* out = (float*)d_out;

    // ws layout: bf16 region, then zero-init fp32/int block, then rest
    __hip_bfloat16* hb    = (__hip_bfloat16*)d_ws;            // NN*HH
    __hip_bfloat16* hwb   = hb + (size_t)NN * HH;             // NN*HH
    __hip_bfloat16* Wb_in = hwb + (size_t)NN * HH;            // HH*DIN
    __hip_bfloat16* Wgb   = Wb_in + (size_t)HH * DIN;         // 2*HH*HH
    float* zbase = (float*)(Wgb + (size_t)2 * HH * HH);
    float* s1_0 = zbase;                 // NN
    float* s2_0 = s1_0 + NN;             // NN
    float* St_0 = s2_0 + NN;             // HH
    float* s1_1 = St_0 + HH;             // NN
    float* s2_1 = s1_1 + NN;             // NN
    float* St_1 = s2_1 + NN;             // HH
    int* cnt  = (int*)(St_1 + HH);       // NN
    int* cnt2 = cnt + NN;                // NN
    size_t zcount = (size_t)2 * (2 * NN + HH) + 2 * NN;  // elements (4B each)
    float* gate = (float*)(cnt2 + NN);   // NN
    int* row_start = (int*)(gate + NN);  // NN+1
    int* col = row_start + NN + 1;       // EE

    const int* src = ei;
    const int* tgt = ei + EE;

    // single zero-fill for score accumulators (both layers) + CSR counters
    hipMemsetAsync(zbase, 0, zcount * 4, stream);

    // weight conversions (one dispatch)
    f2b2<<<(HH * DIN + 2 * HH * HH) / 1024, 256, 0, stream>>>(W_in, Wb_in, HH * DIN, W_gat, Wgb, 2 * HH * HH);

    // CSR build
    count_edges<<<EE / 256, 256, 0, stream>>>(src, cnt);
    scan_deg<<<1, 1024, 0, stream>>>(cnt, row_start);
    fill_edges<<<EE / 256, 256, 0, stream>>>(src, tgt, row_start, cnt2, col);

    // h = X @ W_in^T + b_in
    gemm_f32a<<<dim3(HH / 64, NN / 64), 256, 0, stream>>>(X, Wb_in, b_in, hb, NN, HH, DIN);

    for (int ll = 0; ll < 2; ll++) {
        float* s1 = ll ? s1_1 : s1_0;
        float* s2 = ll ? s2_1 : s2_0;
        float* St = ll ? St_1 : St_0;
        const float* ag = a_gat + (size_t)ll * 2 * HH;
        gemm_bb_score<<<dim3(HH / 64, NN / 64), 256, 0, stream>>>(hb, Wgb + (size_t)ll * HH * HH, hwb,
                                                                  ag, ag + HH, s1, s2, St, NN, HH, HH);
        gat_row<<<NN / 4, 256, 0, stream>>>(hb, hwb, row_start, col, s1, s2, St,
                                            ln_g + (size_t)ll * HH, ln_b + (size_t)ll * HH,
                                            W_pool, b_pool,
                                            (ll == 1) ? out : nullptr, hb, gate, ll);
    }

    hipMemsetAsync(out + (size_t)NN * HH, 0, HH * sizeof(float), stream);
    pool_kernel<<<NN / 32, 256, 0, stream>>>(out, gate, out + (size_t)NN * HH);
}